// Round 10
// baseline (196.793 us; speedup 1.0000x reference)
//
#include <hip/hip_runtime.h>
#include <hip/hip_bf16.h>
#include <stdint.h>

#define T_DIM 4096
#define H_DIM 1024
#define I_DIM 2048

typedef __bf16 bf16x8 __attribute__((ext_vector_type(8)));
typedef float f32x4 __attribute__((ext_vector_type(4)));
typedef unsigned short ushort_t;
typedef unsigned short us4 __attribute__((ext_vector_type(4)));

__device__ __forceinline__ unsigned short f32_to_bf16(float f) {
  unsigned int u = __float_as_uint(f);
  u += 0x7fffu + ((u >> 16) & 1u);  // RNE
  return (unsigned short)(u >> 16);
}

__device__ __forceinline__ void gload_lds16(const void* g, void* l) {
  __builtin_amdgcn_global_load_lds(
      (__attribute__((address_space(1))) void*)(uintptr_t)g,
      (__attribute__((address_space(3))) void*)(unsigned int)(uintptr_t)l,
      16, 0, 0);
}

// XOR swizzle (involution, bits 4-6 ^= bits 7-9 of within-unit byte offset).
// Verified R4: SQ_LDS_BANK_CONFLICT 6.29M -> 0. Transparent to +1024*n adds.
__device__ __forceinline__ int swz(int L) { return L ^ (((L >> 7) & 7) << 4); }

#define S_BARRIER() asm volatile("s_barrier" ::: "memory")
#define WAITV(n) asm volatile("s_waitcnt vmcnt(" #n ")" ::: "memory")
#define IRFENCE() asm volatile("" ::: "memory")
#define MFMA16(acc, va, vb) \
  acc = __builtin_amdgcn_mfma_f32_16x16x32_bf16(va, vb, acc, 0, 0, 0)

// ------- rmsnorm + out-init fused ---------------------------------------------
__global__ __launch_bounds__(256) void k_rmsnorm_init(
    const float* __restrict__ x, const float* __restrict__ scale,
    const float* __restrict__ b2, ushort_t* __restrict__ normed,
    float* __restrict__ out) {
  const int row = blockIdx.x, tid = threadIdx.x;
  const float4 v = ((const float4*)(x + (size_t)row * H_DIM))[tid];
  float ss = v.x * v.x + v.y * v.y + v.z * v.z + v.w * v.w;
#pragma unroll
  for (int off = 32; off > 0; off >>= 1) ss += __shfl_xor(ss, off);
  __shared__ float wsum[4];
  if ((tid & 63) == 0) wsum[tid >> 6] = ss;
  __syncthreads();
  const float tot = wsum[0] + wsum[1] + wsum[2] + wsum[3];
  const float inv = rsqrtf(tot * (1.0f / H_DIM) + 1e-5f);
  const float4 sc = ((const float4*)scale)[tid];
  us4 o;
  o.x = f32_to_bf16(v.x * inv * sc.x);
  o.y = f32_to_bf16(v.y * inv * sc.y);
  o.z = f32_to_bf16(v.z * inv * sc.z);
  o.w = f32_to_bf16(v.w * inv * sc.w);
  ((us4*)(normed + (size_t)row * H_DIM))[tid] = o;
  const float4 b0 = ((const float4*)b2)[tid];
  const float4 b1 = ((const float4*)(b2 + H_DIM))[tid];
  float4 ov;
  ov.x = v.x + 0.5f * (b0.x + b1.x);
  ov.y = v.y + 0.5f * (b0.y + b1.y);
  ov.z = v.z + 0.5f * (b0.z + b1.z);
  ov.w = v.w + 0.5f * (b0.w + b1.w);
  ((float4*)(out + (size_t)row * H_DIM))[tid] = ov;
}

// ------- transpose+convert: src[R][C] f32 -> dst[C][R] bf16 (per blockIdx.z) ---
__global__ __launch_bounds__(256) void k_transpose_cvt(const float* __restrict__ src,
                                                       ushort_t* __restrict__ dst,
                                                       int R, int C) {
  __shared__ float tile[32][33];
  const size_t eoff = (size_t)blockIdx.z * (size_t)R * (size_t)C;
  src += eoff;
  dst += eoff;
  const int x0 = blockIdx.x * 32, y0 = blockIdx.y * 32;
  const int tx = threadIdx.x & 31, ty = threadIdx.x >> 5;
#pragma unroll
  for (int i = 0; i < 4; ++i)
    tile[ty + 8 * i][tx] = src[(size_t)(y0 + ty + 8 * i) * C + x0 + tx];
  __syncthreads();
#pragma unroll
  for (int i = 0; i < 4; ++i)
    dst[(size_t)(x0 + ty + 8 * i) * R + y0 + tx] = f32_to_bf16(tile[tx][ty + 8 * i]);
}

// ---------------- GEMM1: 4 waves of 128x128, 1 block/CU, MFMA-bound ------------
// Block 256 rows x (128g+128l). Wave (wm,wn): rows wm*128, cols wn*64 (g and l).
// acc = accg[8][4]+accl[8][4] = 256 VGPR. Per K-half: 16 ds_read, 8 stage
// loads, 64 MFMA (4:1 MFMA:read). Sync ring = R6's (counts scaled to 8):
// WAITV(8)+BARRIER once per half. LDS 128 KiB: per buf {A_ks0,B_ks0,A_ks1,
// B_ks1} 16 KB units; B unit = Bg 8K + Bl 8K.
__global__ __launch_bounds__(256, 1) void k_gemm1(
    const ushort_t* __restrict__ normed, const ushort_t* __restrict__ w1T,
    const float* __restrict__ b1, ushort_t* __restrict__ act) {
  __shared__ __align__(16) ushort_t lds[2][4][8192];  // 128 KiB
  char* const ldsB = (char*)&lds[0][0][0];
  const int tid = threadIdx.x;
  const int wg = (blockIdx.x & 7) * 64 + (blockIdx.x >> 3);  // XCD swizzle
  const int e = wg >> 8;
  const int rem = wg & 255;
  const int brow = (rem >> 4) * 256;
  const int bcol = (rem & 15) * 128;
  const int lane = tid & 63;
  const int wid = tid >> 6;        // 4 waves
  const int wm = wid >> 1;         // 0..1 -> 128 rows
  const int wn = wid & 1;          // 0..1 -> 64 g-cols + 64 l-cols
  const int r16 = lane & 15, kh = lane >> 4;

  const ushort_t* gBase = w1T + ((size_t)e * 2 * I_DIM + bcol) * H_DIM;
  const ushort_t* lBase = gBase + (size_t)I_DIM * H_DIM;

  f32x4 accg[8][4], accl[8][4];
  const f32x4 zf = {0.f, 0.f, 0.f, 0.f};
#pragma unroll
  for (int m = 0; m < 8; ++m)
#pragma unroll
    for (int n = 0; n < 4; ++n) { accg[m][n] = zf; accl[m][n] = zf; }

  // Staging: 4 chunks per 16 KB unit (256 thr x 16 B = 4 KB/chunk).
  // Pre-swizzled source, linear LDS dest (rule 21).
  const ushort_t* pA[4];
  const ushort_t* pB[4];
#pragma unroll
  for (int j = 0; j < 4; ++j) {
    const int u = swz((j * 256 + tid) * 16);  // within 16 KB unit
    const int col = (u & 63) >> 1;
    pA[j] = normed + (size_t)(brow + (u >> 6)) * H_DIM + col;
    if (u < 8192)
      pB[j] = gBase + (size_t)(u >> 6) * H_DIM + col;
    else
      pB[j] = lBase + (size_t)((u - 8192) >> 6) * H_DIM + col;
  }
  const int ldst0 = (tid & ~63) * 16;  // wave-chunk byte base (0..3072)

  // Fragment bases: one value + literal offsets (swizzle transparent to
  // +1024*m, +1024*n, wm*8192, wn*4096, ks*32768, buf*65536).
  const int abase = wm * 8192 + swz(r16 * 64 + kh * 16);
  const int bbase = 16384 + wn * 4096 + swz(r16 * 64 + kh * 16);

  auto stageA = [&](int buf, int ks) {
#pragma unroll
    for (int j = 0; j < 4; ++j)
      gload_lds16(pA[j] + ks * 32,
                  ldsB + buf * 65536 + ks * 32768 + j * 4096 + ldst0);
  };
  auto stageB = [&](int buf, int ks) {
#pragma unroll
    for (int j = 0; j < 4; ++j)
      gload_lds16(pB[j] + ks * 32,
                  ldsB + buf * 65536 + ks * 32768 + 16384 + j * 4096 + ldst0);
  };

  bf16x8 a[8], bg[4], bl[4];

#define RD_FRAGS(C, KS)                                                       \
  _Pragma("unroll") for (int m = 0; m < 8; ++m)                               \
      a[m] = *(const bf16x8*)(ldsB + (C) * 65536 + (KS) * 32768 + abase +     \
                              m * 1024);                                      \
  _Pragma("unroll") for (int n = 0; n < 4; ++n) {                             \
    bg[n] = *(const bf16x8*)(ldsB + (C) * 65536 + (KS) * 32768 + bbase +      \
                             n * 1024);                                       \
    bl[n] = *(const bf16x8*)(ldsB + (C) * 65536 + (KS) * 32768 + bbase +      \
                             8192 + n * 1024);                                \
  }
#define MFMA_ALL()                                                            \
  _Pragma("unroll") for (int m = 0; m < 8; ++m)                               \
      _Pragma("unroll") for (int n = 0; n < 4; ++n) {                         \
    MFMA16(accg[m][n], a[m], bg[n]);                                          \
    MFMA16(accl[m][n], a[m], bl[n]);                                          \
  }

#define G1_ADV()                                                              \
  {                                                                           \
    _Pragma("unroll") for (int j = 0; j < 4; ++j) { pA[j] += 64; pB[j] += 64; } \
  }

#define G1_HALF(C, N, KS)                                                     \
  {                                                                           \
    RD_FRAGS(C, KS);                                                          \
    stageA(N, KS);                                                            \
    stageB(N, KS);                                                            \
    __builtin_amdgcn_s_setprio(1);                                            \
    MFMA_ALL();                                                               \
    __builtin_amdgcn_s_setprio(0);                                            \
    WAITV(8);                                                                 \
    S_BARRIER();                                                              \
  }

#define G1_TILE(C, N)  \
  { G1_HALF(C, N, 0); G1_HALF(C, N, 1); G1_ADV(); }

  // Prologue: stage tile 0 (ks0 then ks1), advance, drain ks0 (ks1 in flight).
  stageA(0, 0); stageB(0, 0); IRFENCE();
  stageA(0, 1); stageB(0, 1);
  G1_ADV();
  WAITV(8);
  S_BARRIER();

#pragma unroll 1
  for (int it = 0; it < 7; ++it) {  // tiles 0..13
    G1_TILE(0, 1);
    G1_TILE(1, 0);
  }
  G1_TILE(0, 1);  // tile 14, stages tile 15 into buf1

  // Tail: tile 15 in buf1 (ks0 drained by tile14's last WAITV; ks1 in flight).
  {
    RD_FRAGS(1, 0);
    MFMA_ALL();
    WAITV(0);
    S_BARRIER();  // all waves' ks1 staging drained
    RD_FRAGS(1, 1);
    MFMA_ALL();
  }
#undef G1_HALF
#undef G1_TILE
#undef G1_ADV
#undef RD_FRAGS
#undef MFMA_ALL

  // Epilogue: bias + clip + sigmoid-gate, store bf16 act.
  const float* b1e = b1 + (size_t)e * 2 * I_DIM;
#pragma unroll
  for (int m = 0; m < 8; ++m)
#pragma unroll
    for (int n = 0; n < 4; ++n) {
      const int gcol = bcol + wn * 64 + n * 16 + r16;
      const float bgb = b1e[gcol];
      const float blb = b1e[I_DIM + gcol];
#pragma unroll
      for (int rr = 0; rr < 4; ++rr) {
        const int grow = brow + wm * 128 + m * 16 + kh * 4 + rr;
        const float hg = accg[m][n][rr] + bgb;
        const float hl = accl[m][n][rr] + blb;
        const float g = fminf(hg, 7.f);
        const float l = fminf(fmaxf(hl, -7.f), 7.f);
        const float s = 1.f / (1.f + __expf(-1.702f * g));
        const float av = g * s * (l + 1.f);
        act[((size_t)e * T_DIM + grow) * I_DIM + gcol] = f32_to_bf16(av);
      }
    }
}

// ---------------- GEMM2: 4 waves of 128x128, block 256x256, split-K=4 ----------
// Grid bid = kc*64 + tile (kc = e*2+ih): 64%8==0 -> all 4 kc-partials of a
// tile land on the SAME XCD (bid%8 = tile%8) -> atomics resolve in one L2.
// LDS 128 KiB: per buf {A_ks0(16K), B_ks0(16K), A_ks1, B_ks1}.
__global__ __launch_bounds__(256, 1) void k_gemm2(
    const ushort_t* __restrict__ act, const ushort_t* __restrict__ w2T,
    float* __restrict__ out) {
  __shared__ __align__(16) ushort_t lds[2][4][8192];  // 128 KiB
  char* const ldsB = (char*)&lds[0][0][0];
  const int tid = threadIdx.x;
  const int bid = blockIdx.x;
  const int kc = bid >> 6;          // 0..3: e = kc>>1, ih = kc&1
  const int tile = bid & 63;        // 16 rowtiles x 4 coltiles
  const int e = kc >> 1, ih = kc & 1;
  const int brow = (tile >> 2) * 256;
  const int bcol = (tile & 3) * 256;
  const int lane = tid & 63;
  const int wid = tid >> 6;
  const int wm = wid >> 1;          // 0..1
  const int wn = wid & 1;           // 0..1
  const int r16 = lane & 15, kh = lane >> 4;

  const ushort_t* aBase = act + ((size_t)e * T_DIM + brow) * I_DIM + ih * 1024;
  const ushort_t* bBase = w2T + ((size_t)e * H_DIM + bcol) * I_DIM + ih * 1024;

  f32x4 acc[8][8];
  const f32x4 zf = {0.f, 0.f, 0.f, 0.f};
#pragma unroll
  for (int m = 0; m < 8; ++m)
#pragma unroll
    for (int n = 0; n < 8; ++n) acc[m][n] = zf;

  const ushort_t* pA[4];
  const ushort_t* pB[4];
#pragma unroll
  for (int j = 0; j < 4; ++j) {
    const int u = swz((j * 256 + tid) * 16);
    const int col = (u & 63) >> 1;
    pA[j] = aBase + (size_t)(u >> 6) * I_DIM + col;
    pB[j] = bBase + (size_t)(u >> 6) * I_DIM + col;
  }
  const int ldst0 = (tid & ~63) * 16;

  const int abase = wm * 8192 + swz(r16 * 64 + kh * 16);
  const int bbase = 16384 + wn * 8192 + swz(r16 * 64 + kh * 16);

  auto stageA = [&](int buf, int ks) {
#pragma unroll
    for (int j = 0; j < 4; ++j)
      gload_lds16(pA[j] + ks * 32,
                  ldsB + buf * 65536 + ks * 32768 + j * 4096 + ldst0);
  };
  auto stageB = [&](int buf, int ks) {
#pragma unroll
    for (int j = 0; j < 4; ++j)
      gload_lds16(pB[j] + ks * 32,
                  ldsB + buf * 65536 + ks * 32768 + 16384 + j * 4096 + ldst0);
  };

  bf16x8 a[8], b[8];

#define RD_FRAGS(C, KS)                                                       \
  _Pragma("unroll") for (int m = 0; m < 8; ++m)                               \
      a[m] = *(const bf16x8*)(ldsB + (C) * 65536 + (KS) * 32768 + abase +     \
                              m * 1024);                                      \
  _Pragma("unroll") for (int n = 0; n < 8; ++n)                               \
      b[n] = *(const bf16x8*)(ldsB + (C) * 65536 + (KS) * 32768 + bbase +     \
                              n * 1024);
#define MFMA_ALL()                                                            \
  _Pragma("unroll") for (int m = 0; m < 8; ++m)                               \
      _Pragma("unroll") for (int n = 0; n < 8; ++n)                           \
          MFMA16(acc[m][n], a[m], b[n]);

#define G2_ADV()                                                              \
  {                                                                           \
    _Pragma("unroll") for (int j = 0; j < 4; ++j) { pA[j] += 64; pB[j] += 64; } \
  }

#define G2_HALF(C, N, KS)                                                     \
  {                                                                           \
    RD_FRAGS(C, KS);                                                          \
    stageA(N, KS);                                                            \
    stageB(N, KS);                                                            \
    __builtin_amdgcn_s_setprio(1);                                            \
    MFMA_ALL();                                                               \
    __builtin_amdgcn_s_setprio(0);                                            \
    WAITV(8);                                                                 \
    S_BARRIER();                                                              \
  }

#define G2_TILE(C, N)  \
  { G2_HALF(C, N, 0); G2_HALF(C, N, 1); G2_ADV(); }

  stageA(0, 0); stageB(0, 0); IRFENCE();
  stageA(0, 1); stageB(0, 1);
  G2_ADV();
  WAITV(8);
  S_BARRIER();

#pragma unroll 1
  for (int it = 0; it < 7; ++it) {  // tiles 0..13 (16 K-tiles total: K=1024)
    G2_TILE(0, 1);
    G2_TILE(1, 0);
  }
  G2_TILE(0, 1);  // tile 14, stages tile 15 into buf1

  // Tail: tile 15 in buf1.
  {
    RD_FRAGS(1, 0);
    MFMA_ALL();
    WAITV(0);
    S_BARRIER();
    RD_FRAGS(1, 1);
    MFMA_ALL();
  }
#undef G2_HALF
#undef G2_TILE
#undef G2_ADV
#undef RD_FRAGS
#undef MFMA_ALL

  // Epilogue: atomic accumulate 0.5*acc into out (pre-initialized x + bias).
  // All 4 kc-partials of this tile are on the same XCD (grid mapping above).
#pragma unroll
  for (int m = 0; m < 8; ++m)
#pragma unroll
    for (int n = 0; n < 8; ++n) {
      const int gcol = bcol + wn * 128 + n * 16 + r16;
#pragma unroll
      for (int rr = 0; rr < 4; ++rr) {
        const int grow = brow + wm * 128 + m * 16 + kh * 4 + rr;
        atomicAdd(&out[(size_t)grow * H_DIM + gcol], 0.5f * acc[m][n][rr]);
      }
    }
}

extern "C" void kernel_launch(void* const* d_in, const int* in_sizes, int n_in,
                              void* d_out, int out_size, void* d_ws, size_t ws_size,
                              hipStream_t stream) {
  const float* x = (const float*)d_in[0];
  const float* scale = (const float*)d_in[1];
  // d_in[2]=gate_kernel, d_in[3]=gate_bias: static routing, logits unused.
  const float* w1 = (const float*)d_in[4];
  const float* b1 = (const float*)d_in[5];
  const float* w2 = (const float*)d_in[6];
  const float* b2 = (const float*)d_in[7];
  float* out = (float*)d_out;

  ushort_t* ws = (ushort_t*)d_ws;
  ushort_t* normed = ws;                                    // [T][H]
  ushort_t* w1T = normed + (size_t)T_DIM * H_DIM;           // [2][2I][H]
  ushort_t* w2T = w1T + (size_t)2 * 2 * I_DIM * H_DIM;      // [2][H][I]
  ushort_t* actb = w2T + (size_t)2 * H_DIM * I_DIM;         // [2][T][I]

  k_rmsnorm_init<<<dim3(T_DIM), 256, 0, stream>>>(x, scale, b2, normed, out);
  k_transpose_cvt<<<dim3(2 * I_DIM / 32, H_DIM / 32, 2), 256, 0, stream>>>(
      w1, w1T, H_DIM, 2 * I_DIM);
  k_transpose_cvt<<<dim3(H_DIM / 32, I_DIM / 32, 2), 256, 0, stream>>>(
      w2, w2T, I_DIM, H_DIM);
  k_gemm1<<<dim3(512), 256, 0, stream>>>(normed, w1T, b1, actb);
  k_gemm2<<<dim3(256), 256, 0, stream>>>(actb, w2T, out);
}

// Round 11
// 154.398 us; speedup vs baseline: 1.2746x; 1.2746x over previous
//
#include <hip/hip_runtime.h>
#include <hip/hip_bf16.h>
#include <stdint.h>

#define T_DIM 4096
#define H_DIM 1024
#define I_DIM 2048

typedef __bf16 bf16x8 __attribute__((ext_vector_type(8)));
typedef float f32x4 __attribute__((ext_vector_type(4)));
typedef unsigned short ushort_t;
typedef unsigned short us4 __attribute__((ext_vector_type(4)));

__device__ __forceinline__ unsigned short f32_to_bf16(float f) {
  unsigned int u = __float_as_uint(f);
  u += 0x7fffu + ((u >> 16) & 1u);  // RNE
  return (unsigned short)(u >> 16);
}

__device__ __forceinline__ void gload_lds16(const void* g, void* l) {
  __builtin_amdgcn_global_load_lds(
      (__attribute__((address_space(1))) void*)(uintptr_t)g,
      (__attribute__((address_space(3))) void*)(unsigned int)(uintptr_t)l,
      16, 0, 0);
}

// XOR swizzle within an 8KB [128][32]bf16 unit (involution; bits 4-6 ^= 7-9).
// Verified R4: SQ_LDS_BANK_CONFLICT 6.29M -> 0. Transparent to +1024*n,
// +4096*w, +unit/buf strides (no carries into bits 7-9).
__device__ __forceinline__ int swz(int L) { return L ^ (((L >> 7) & 7) << 4); }

#define S_BARRIER() asm volatile("s_barrier" ::: "memory")
#define WAITV(n) asm volatile("s_waitcnt vmcnt(" #n ")" ::: "memory")
#define IRFENCE() asm volatile("" ::: "memory")
#define MFMA16(acc, va, vb) \
  acc = __builtin_amdgcn_mfma_f32_16x16x32_bf16(va, vb, acc, 0, 0, 0)

// ------- rmsnorm + out-init fused ---------------------------------------------
__global__ __launch_bounds__(256) void k_rmsnorm_init(
    const float* __restrict__ x, const float* __restrict__ scale,
    const float* __restrict__ b2, ushort_t* __restrict__ normed,
    float* __restrict__ out) {
  const int row = blockIdx.x, tid = threadIdx.x;
  const float4 v = ((const float4*)(x + (size_t)row * H_DIM))[tid];
  float ss = v.x * v.x + v.y * v.y + v.z * v.z + v.w * v.w;
#pragma unroll
  for (int off = 32; off > 0; off >>= 1) ss += __shfl_xor(ss, off);
  __shared__ float wsum[4];
  if ((tid & 63) == 0) wsum[tid >> 6] = ss;
  __syncthreads();
  const float tot = wsum[0] + wsum[1] + wsum[2] + wsum[3];
  const float inv = rsqrtf(tot * (1.0f / H_DIM) + 1e-5f);
  const float4 sc = ((const float4*)scale)[tid];
  us4 o;
  o.x = f32_to_bf16(v.x * inv * sc.x);
  o.y = f32_to_bf16(v.y * inv * sc.y);
  o.z = f32_to_bf16(v.z * inv * sc.z);
  o.w = f32_to_bf16(v.w * inv * sc.w);
  ((us4*)(normed + (size_t)row * H_DIM))[tid] = o;
  const float4 b0 = ((const float4*)b2)[tid];
  const float4 b1 = ((const float4*)(b2 + H_DIM))[tid];
  float4 ov;
  ov.x = v.x + 0.5f * (b0.x + b1.x);
  ov.y = v.y + 0.5f * (b0.y + b1.y);
  ov.z = v.z + 0.5f * (b0.z + b1.z);
  ov.w = v.w + 0.5f * (b0.w + b1.w);
  ((float4*)(out + (size_t)row * H_DIM))[tid] = ov;
}

// ------- transpose+convert: src[R][C] f32 -> dst[C][R] bf16 (per blockIdx.z) ---
__global__ __launch_bounds__(256) void k_transpose_cvt(const float* __restrict__ src,
                                                       ushort_t* __restrict__ dst,
                                                       int R, int C) {
  __shared__ float tile[32][33];
  const size_t eoff = (size_t)blockIdx.z * (size_t)R * (size_t)C;
  src += eoff;
  dst += eoff;
  const int x0 = blockIdx.x * 32, y0 = blockIdx.y * 32;
  const int tx = threadIdx.x & 31, ty = threadIdx.x >> 5;
#pragma unroll
  for (int i = 0; i < 4; ++i)
    tile[ty + 8 * i][tx] = src[(size_t)(y0 + ty + 8 * i) * C + x0 + tx];
  __syncthreads();
#pragma unroll
  for (int i = 0; i < 4; ++i)
    dst[(size_t)(x0 + ty + 8 * i) * R + y0 + tx] = f32_to_bf16(tile[tx][ty + 8 * i]);
}

// ---------------- GEMM1: 128 x (128g+128l), BK=32, tri-buffer, 2 blocks/CU -----
// 4 waves 2(wm)x2(wn); wave 64 rows x 64 paircols; acc 4x(4+4) = 128 VGPR.
// LDS 72 KiB = 3 bufs x {A[128][32] 8K, Bg 8K, Bl 8K}. Stage 2 tiles ahead
// (6 loads/tile, WAITV(6)/step). Inter-block overlap (m114) via 2 blocks/CU.
__global__ __launch_bounds__(256, 2) void k_gemm1(
    const ushort_t* __restrict__ normed, const ushort_t* __restrict__ w1T,
    const float* __restrict__ b1, ushort_t* __restrict__ act) {
  __shared__ __align__(16) ushort_t lds[3][3][4096];  // 72 KiB
  char* const ldsB = (char*)&lds[0][0][0];
  const int tid = threadIdx.x;
  const int wg = (blockIdx.x & 7) * 128 + (blockIdx.x >> 3);  // XCD swizzle, 1024%8==0
  const int e = wg >> 9;
  const int rem = wg & 511;
  const int brow = (rem >> 4) * 128;   // 32 rowtiles
  const int bcol = (rem & 15) * 128;   // 16 paircol tiles
  const int lane = tid & 63;
  const int wid = tid >> 6;
  const int wm = wid >> 1, wn = wid & 1;
  const int r16 = lane & 15, kh = lane >> 4;

  const ushort_t* gBase = w1T + ((size_t)e * 2 * I_DIM + bcol) * H_DIM;
  const ushort_t* lBase = w1T + ((size_t)e * 2 * I_DIM + I_DIM + bcol) * H_DIM;

  f32x4 accg[4][4], accl[4][4];
  const f32x4 zf = {0.f, 0.f, 0.f, 0.f};
#pragma unroll
  for (int m = 0; m < 4; ++m)
#pragma unroll
    for (int n = 0; n < 4; ++n) { accg[m][n] = zf; accl[m][n] = zf; }

  // Staging decomposition: 2 chunks per 8KB unit (pre-swizzled src, rule 21).
  const ushort_t* pA[2];
  const ushort_t* pG[2];
  const ushort_t* pL[2];
#pragma unroll
  for (int j = 0; j < 2; ++j) {
    const int u = swz(j * 4096 + tid * 16);
    const int r = u >> 6, c = (u & 63) >> 1;
    pA[j] = normed + (size_t)(brow + r) * H_DIM + c;
    pG[j] = gBase + (size_t)r * H_DIM + c;
    pL[j] = lBase + (size_t)r * H_DIM + c;
  }
  const int ldst0 = (tid & ~63) * 16;

  const int abase = swz((wm * 64 + r16) * 64 + kh * 16);
  const int bbase = 8192 + swz((wn * 64 + r16) * 64 + kh * 16);

  auto stage = [&](int buf) {
#pragma unroll
    for (int j = 0; j < 2; ++j) {
      gload_lds16(pA[j], ldsB + buf * 24576 + j * 4096 + ldst0);
      gload_lds16(pG[j], ldsB + buf * 24576 + 8192 + j * 4096 + ldst0);
      gload_lds16(pL[j], ldsB + buf * 24576 + 16384 + j * 4096 + ldst0);
    }
  };

  bf16x8 a[4], bg[4], bl[4];

#define G1_ADV()                                                              \
  {                                                                           \
    _Pragma("unroll") for (int j = 0; j < 2; ++j) {                           \
      pA[j] += 32; pG[j] += 32; pL[j] += 32;                                  \
    }                                                                         \
  }
#define G1_RD(C)                                                              \
  _Pragma("unroll") for (int m = 0; m < 4; ++m)                               \
      a[m] = *(const bf16x8*)(ldsB + (C) * 24576 + abase + m * 1024);         \
  _Pragma("unroll") for (int n = 0; n < 4; ++n) {                             \
    bg[n] = *(const bf16x8*)(ldsB + (C) * 24576 + bbase + n * 1024);          \
    bl[n] = *(const bf16x8*)(ldsB + (C) * 24576 + bbase + 8192 + n * 1024);   \
  }
#define G1_MFMA()                                                             \
  _Pragma("unroll") for (int m = 0; m < 4; ++m)                               \
      _Pragma("unroll") for (int n = 0; n < 4; ++n) {                         \
    MFMA16(accg[m][n], a[m], bg[n]);                                          \
    MFMA16(accl[m][n], a[m], bl[n]);                                          \
  }
#define G1_STEP(C, N)                                                         \
  {                                                                           \
    G1_RD(C);                                                                 \
    stage(N);                                                                 \
    __builtin_amdgcn_s_setprio(1);                                            \
    G1_MFMA();                                                                \
    __builtin_amdgcn_s_setprio(0);                                            \
    WAITV(6);                                                                 \
    S_BARRIER();                                                              \
    G1_ADV();                                                                 \
  }

  // Prologue: stage t0->b0, t1->b1 (12 out); WAITV(6) -> t0 landed.
  stage(0); IRFENCE();
  G1_ADV();
  stage(1);
  G1_ADV();
  WAITV(6);
  S_BARRIER();

#pragma unroll 1
  for (int it = 0; it < 10; ++it) {  // steps t=0..29, staging t+2 (<=31)
    G1_STEP(0, 2);
    G1_STEP(1, 0);
    G1_STEP(2, 1);
  }
  // Tail: t=30 (b0; landed via step29's WAITV), t=31 (b1; in flight).
  {
    G1_RD(0);
    G1_MFMA();
    WAITV(0);
    S_BARRIER();  // all waves' t31 staging drained
    G1_RD(1);
    G1_MFMA();
  }
#undef G1_STEP
#undef G1_MFMA
#undef G1_RD
#undef G1_ADV

  // Epilogue: bias + clip + sigmoid-gate, store bf16 act.
  const float* b1e = b1 + (size_t)e * 2 * I_DIM;
#pragma unroll
  for (int m = 0; m < 4; ++m)
#pragma unroll
    for (int n = 0; n < 4; ++n) {
      const int gcol = bcol + wn * 64 + n * 16 + r16;
      const float bgb = b1e[gcol];
      const float blb = b1e[I_DIM + gcol];
#pragma unroll
      for (int rr = 0; rr < 4; ++rr) {
        const int grow = brow + wm * 64 + m * 16 + kh * 4 + rr;
        const float hg = accg[m][n][rr] + bgb;
        const float hl = accl[m][n][rr] + blb;
        const float g = fminf(hg, 7.f);
        const float l = fminf(fmaxf(hl, -7.f), 7.f);
        const float s = 1.f / (1.f + __expf(-1.702f * g));
        const float av = g * s * (l + 1.f);
        act[((size_t)e * T_DIM + grow) * I_DIM + gcol] = f32_to_bf16(av);
      }
    }
}

// ---------------- GEMM2: 128x128, split-K=2 (expert), BK=32, 3 blocks/CU -------
// 4 waves 2x2; wave 64x64; acc 16 f32x4. LDS 48 KiB = 3 bufs x {A 8K, B 8K}.
// 4 loads/tile, WAITV(4)/step, stage 2 ahead.
__global__ __launch_bounds__(256, 3) void k_gemm2(
    const ushort_t* __restrict__ act, const ushort_t* __restrict__ w2T,
    float* __restrict__ out) {
  __shared__ __align__(16) ushort_t lds[3][2][4096];  // 48 KiB
  char* const ldsB = (char*)&lds[0][0][0];
  const int tid = threadIdx.x;
  const int wg = (blockIdx.x & 7) * 64 + (blockIdx.x >> 3);  // 512%8==0
  const int e = wg >> 8;
  const int rem = wg & 255;
  const int brow = (rem >> 3) * 128;  // 32 rowtiles
  const int bcol = (rem & 7) * 128;   // 8 coltiles
  const int lane = tid & 63;
  const int wid = tid >> 6;
  const int wm = wid >> 1, wn = wid & 1;
  const int r16 = lane & 15, kh = lane >> 4;

  const ushort_t* aBase = act + ((size_t)e * T_DIM + brow) * I_DIM;
  const ushort_t* bBase = w2T + ((size_t)e * H_DIM + bcol) * I_DIM;

  f32x4 acc[4][4];
  const f32x4 zf = {0.f, 0.f, 0.f, 0.f};
#pragma unroll
  for (int m = 0; m < 4; ++m)
#pragma unroll
    for (int n = 0; n < 4; ++n) acc[m][n] = zf;

  const ushort_t* pA[2];
  const ushort_t* pB[2];
#pragma unroll
  for (int j = 0; j < 2; ++j) {
    const int u = swz(j * 4096 + tid * 16);
    const int r = u >> 6, c = (u & 63) >> 1;
    pA[j] = aBase + (size_t)r * I_DIM + c;
    pB[j] = bBase + (size_t)r * I_DIM + c;
  }
  const int ldst0 = (tid & ~63) * 16;

  const int abase = swz((wm * 64 + r16) * 64 + kh * 16);
  const int bbase = 8192 + swz((wn * 64 + r16) * 64 + kh * 16);

  auto stage = [&](int buf) {
#pragma unroll
    for (int j = 0; j < 2; ++j) {
      gload_lds16(pA[j], ldsB + buf * 16384 + j * 4096 + ldst0);
      gload_lds16(pB[j], ldsB + buf * 16384 + 8192 + j * 4096 + ldst0);
    }
  };

  bf16x8 a[4], b[4];

#define G2_ADV()                                                              \
  {                                                                           \
    _Pragma("unroll") for (int j = 0; j < 2; ++j) { pA[j] += 32; pB[j] += 32; } \
  }
#define G2_RD(C)                                                              \
  _Pragma("unroll") for (int m = 0; m < 4; ++m)                               \
      a[m] = *(const bf16x8*)(ldsB + (C) * 16384 + abase + m * 1024);         \
  _Pragma("unroll") for (int n = 0; n < 4; ++n)                               \
      b[n] = *(const bf16x8*)(ldsB + (C) * 16384 + bbase + n * 1024);
#define G2_MFMA()                                                             \
  _Pragma("unroll") for (int m = 0; m < 4; ++m)                               \
      _Pragma("unroll") for (int n = 0; n < 4; ++n)                           \
          MFMA16(acc[m][n], a[m], b[n]);
#define G2_STEP(C, N)                                                         \
  {                                                                           \
    G2_RD(C);                                                                 \
    stage(N);                                                                 \
    __builtin_amdgcn_s_setprio(1);                                            \
    G2_MFMA();                                                                \
    __builtin_amdgcn_s_setprio(0);                                            \
    WAITV(4);                                                                 \
    S_BARRIER();                                                              \
    G2_ADV();                                                                 \
  }

  // Prologue: stage t0->b0, t1->b1 (8 out); WAITV(4) -> t0 landed.
  stage(0); IRFENCE();
  G2_ADV();
  stage(1);
  G2_ADV();
  WAITV(4);
  S_BARRIER();

#pragma unroll 1
  for (int it = 0; it < 20; ++it) {  // steps t=0..59, staging t+2 (<=61)
    G2_STEP(0, 2);
    G2_STEP(1, 0);
    G2_STEP(2, 1);
  }
  G2_STEP(0, 2);  // t=60, stages t=62
  G2_STEP(1, 0);  // t=61, stages t=63
  // Tail: t=62 (b2; landed via t61's WAITV), t=63 (b0; in flight).
  {
    G2_RD(2);
    G2_MFMA();
    WAITV(0);
    S_BARRIER();
    G2_RD(0);
    G2_MFMA();
  }
#undef G2_STEP
#undef G2_MFMA
#undef G2_RD
#undef G2_ADV

  // Epilogue: atomic accumulate 0.5*acc into out (pre-initialized x + bias).
#pragma unroll
  for (int m = 0; m < 4; ++m)
#pragma unroll
    for (int n = 0; n < 4; ++n) {
      const int gcol = bcol + wn * 64 + n * 16 + r16;
#pragma unroll
      for (int rr = 0; rr < 4; ++rr) {
        const int grow = brow + wm * 64 + m * 16 + kh * 4 + rr;
        atomicAdd(&out[(size_t)grow * H_DIM + gcol], 0.5f * acc[m][n][rr]);
      }
    }
}

extern "C" void kernel_launch(void* const* d_in, const int* in_sizes, int n_in,
                              void* d_out, int out_size, void* d_ws, size_t ws_size,
                              hipStream_t stream) {
  const float* x = (const float*)d_in[0];
  const float* scale = (const float*)d_in[1];
  // d_in[2]=gate_kernel, d_in[3]=gate_bias: static routing, logits unused.
  const float* w1 = (const float*)d_in[4];
  const float* b1 = (const float*)d_in[5];
  const float* w2 = (const float*)d_in[6];
  const float* b2 = (const float*)d_in[7];
  float* out = (float*)d_out;

  ushort_t* ws = (ushort_t*)d_ws;
  ushort_t* normed = ws;                                    // [T][H]
  ushort_t* w1T = normed + (size_t)T_DIM * H_DIM;           // [2][2I][H]
  ushort_t* w2T = w1T + (size_t)2 * 2 * I_DIM * H_DIM;      // [2][H][I]
  ushort_t* actb = w2T + (size_t)2 * H_DIM * I_DIM;         // [2][T][I]

  k_rmsnorm_init<<<dim3(T_DIM), 256, 0, stream>>>(x, scale, b2, normed, out);
  k_transpose_cvt<<<dim3(2 * I_DIM / 32, H_DIM / 32, 2), 256, 0, stream>>>(
      w1, w1T, H_DIM, 2 * I_DIM);
  k_transpose_cvt<<<dim3(H_DIM / 32, I_DIM / 32, 2), 256, 0, stream>>>(
      w2, w2T, I_DIM, H_DIM);
  k_gemm1<<<dim3(1024), 256, 0, stream>>>(normed, w1T, b1, actb);
  k_gemm2<<<dim3(512), 256, 0, stream>>>(actb, w2T, out);
}